// Round 12
// baseline (180.938 us; speedup 1.0000x reference)
//
#include <hip/hip_runtime.h>
#include <hip/hip_bf16.h>

#define B_TOT 2048
#define N_CAP 200
#define D_DIM 256
#define NT    512
#define NW    8               // waves per block
#define CPW   25              // capsules per wave (200/8, exact)

__device__ __forceinline__ float bf_lo(unsigned u) { return __uint_as_float(u << 16); }
__device__ __forceinline__ float bf_hi(unsigned u) { return __uint_as_float(u & 0xffff0000u); }

__device__ __forceinline__ float wave_sum(float v) {
#pragma unroll
    for (int off = 32; off; off >>= 1) v += __shfl_xor(v, off);
    return v;
}

// Block sum WITHOUT leading barrier: caller must guarantee a __syncthreads()
// executed between the previous read of red[] and this call (WAR safety).
__device__ __forceinline__ float block_sum_nb(float v, float* red, int wave, int lane) {
    v = wave_sum(v);
    if (lane == 0) red[wave] = v;
    __syncthreads();
    float s = 0.f;
#pragma unroll
    for (int i = 0; i < NW; ++i) s += red[i];
    return s;
}

// Anchor = R10 (162us, passed). Deltas kept from R11: pre-staged r=0 exp/red,
// w_lds pass deleted (einsum weight e*inv inline), 4 barriers/iter.
// Delta REVERTED from R11 (which failed, c absmax 133): the in-register
// `if (lane==i) psel = p` gather across 25 unrolled wave_sum chains. Tail now
// uses only HW-proven patterns: R10's lane-0 b-update inside the dot loop +
// R8's same-wave owner-lane exp refresh from b_lds.
// DO NOT: fuse agreement+einsum accumulators (R3/R4: 64-VGPR spill),
// LB(...,8) (R9: 32 VGPR), per-capsule sched_barrier (R6: depth-1 loads),
// LDS-split u (R7), lane-select gather of wave_sum results (R11: wrong c).
__global__ __launch_bounds__(NT, 4)
void dyr_kernel(const float* __restrict__ embeds,
                const float* __restrict__ weights,
                float* __restrict__ out_v,
                float* __restrict__ out_c)
{
    __shared__ float s_part[NW][D_DIM];   // 8 KB
    __shared__ float red[NW];
    __shared__ float b_lds[N_CAP];        // routing logits; wave w owns slots w+8i
    __shared__ float e_lds[N_CAP];        // exp(b)
    __shared__ float inv_lds[N_CAP];      // 1 / max(||x_n||, 1e-12)
    __shared__ float v_lds[D_DIM];

    const int b    = blockIdx.x;
    const int t    = threadIdx.x;
    const int wave = t >> 6;
    const int lane = t & 63;

    // ---- pre-load: logits, r=0 exp, r=0 softmax-denominator partials ----
    float ev = 0.f;
    if (t < N_CAP) {
        const float bw = weights[(size_t)b * N_CAP + t];
        b_lds[t] = bw;
        ev = __expf(bw);        // no max-subtraction: |b| <= ~8, fp32 exp safe (R8/R10)
        e_lds[t] = ev;
    }
    {
        const float esp0 = wave_sum(ev);
        if (lane == 0) red[wave] = esp0;
    }

    // ---- Load embeds ONCE; RAW x -> bf16 regs; 1/||x|| -> LDS.
    // wave w, lane l holds capsule n = w + 8i, dims [4l, 4l+4).
    // 5 chunks x 5 in-flight float4 loads (R2's exact schedule). ----
    const float* eb = embeds + (size_t)b * (N_CAP * D_DIM) + lane * 4;

    uint2 u[CPW];   // 50 VGPRs, raw x packed bf16
#pragma unroll
    for (int cc = 0; cc < 5; ++cc) {
        float4 xs[5];
#pragma unroll
        for (int j = 0; j < 5; ++j) {
            const int n = wave + (cc * 5 + j) * NW;
            xs[j] = *reinterpret_cast<const float4*>(eb + n * D_DIM);
        }
#pragma unroll
        for (int j = 0; j < 5; ++j) {
            const float4 x = xs[j];
            float ss = fmaf(x.x, x.x, fmaf(x.y, x.y, fmaf(x.z, x.z, x.w * x.w)));
            ss = wave_sum(ss);
            if (lane == 0)
                inv_lds[wave + (cc * 5 + j) * NW] = 1.0f / fmaxf(sqrtf(ss), 1e-12f);
            union { __hip_bfloat16 h[4]; uint2 q; } pk;
            pk.h[0] = __float2bfloat16(x.x);
            pk.h[1] = __float2bfloat16(x.y);
            pk.h[2] = __float2bfloat16(x.z);
            pk.h[3] = __float2bfloat16(x.w);
            u[cc * 5 + j] = pk.q;
        }
    }
    __syncthreads();   // publish red/e_lds/b_lds/inv_lds == iteration-0's B1

    // ---- 3 routing iterations: 4 barriers each ----
    for (int r = 0; r < 3; ++r) {
        // softmax scale from staged partials (red visible at loop entry)
        float es = 0.f;
#pragma unroll
        for (int w = 0; w < NW; ++w) es += red[w];
        const float cs = (float)N_CAP / es;

        // einsum partial: acc = cs * sum_i (e_i * inv_i) * x_i
        float4 acc = make_float4(0.f, 0.f, 0.f, 0.f);
#pragma unroll
        for (int i = 0; i < CPW; ++i) {
            const int n = wave + NW * i;
            const float wn = e_lds[n] * inv_lds[n];   // wave-uniform broadcasts
            acc.x = fmaf(wn, bf_lo(u[i].x), acc.x);
            acc.y = fmaf(wn, bf_hi(u[i].x), acc.y);
            acc.z = fmaf(wn, bf_lo(u[i].y), acc.z);
            acc.w = fmaf(wn, bf_hi(u[i].y), acc.w);
        }
        acc.x *= cs; acc.y *= cs; acc.z *= cs; acc.w *= cs;
        *reinterpret_cast<float4*>(&s_part[wave][lane * 4]) = acc;

        if (r == 2 && t < N_CAP)               // c = e * N/es, coalesced
            out_c[(size_t)b * N_CAP + t] = e_lds[t] * cs;
        __syncthreads();                       // B3: s_part visible; red WAR-guard

        // cross-wave reduce + squash
        float sd = 0.f;
        if (t < D_DIM) {
#pragma unroll
            for (int w = 0; w < NW; ++w) sd += s_part[w][t];
        }
        const float ssn = block_sum_nb(sd * sd, red, wave, lane);   // B4
        if (t < D_DIM) {
            const float scale = ssn / (1.0f + ssn) * rsqrtf(ssn + 1e-9f);
            const float vd = scale * sd;
            v_lds[t] = vd;
            if (r == 2) out_v[(size_t)b * D_DIM + t] = vd;
        }

        if (r < 2) {
            __syncthreads();                   // B5: v_lds visible; red WAR-guard
            const float4 vv = *reinterpret_cast<const float4*>(&v_lds[lane * 4]);

            // agreement (R10's proven pattern): lane 0 updates owner slots
#pragma unroll
            for (int i = 0; i < CPW; ++i) {
                float p = fmaf(bf_lo(u[i].x), vv.x,
                          fmaf(bf_hi(u[i].x), vv.y,
                          fmaf(bf_lo(u[i].y), vv.z,
                               bf_hi(u[i].y) * vv.w)));
                p = wave_sum(p);
                if (lane == 0) {
                    const int n = wave + NW * i;
                    b_lds[n] = fmaf(p, inv_lds[n], b_lds[n]);
                }
            }
            // exp refresh (R8's proven pattern): same-wave read-after-write
            float en = 0.f;
            if (lane < CPW) {
                const int n = wave + NW * lane;
                en = __expf(b_lds[n]);
                e_lds[n] = en;
            }
            const float espn = wave_sum(en);
            if (lane == 0) red[wave] = espn;
            __syncthreads();                   // B6: e_lds/b_lds/red visible
        }
    }
}

extern "C" void kernel_launch(void* const* d_in, const int* in_sizes, int n_in,
                              void* d_out, int out_size, void* d_ws, size_t ws_size,
                              hipStream_t stream) {
    const float* embeds  = (const float*)d_in[0];
    const float* weights = (const float*)d_in[1];
    float* out   = (float*)d_out;
    float* out_v = out;                                  // [2048, 256]
    float* out_c = out + (size_t)B_TOT * D_DIM;          // [2048, 200]

    dyr_kernel<<<B_TOT, NT, 0, stream>>>(embeds, weights, out_v, out_c);
}

// Round 13
// 177.975 us; speedup vs baseline: 1.0167x; 1.0167x over previous
//
#include <hip/hip_runtime.h>
#include <hip/hip_bf16.h>

#define B_TOT 2048
#define N_CAP 200
#define D_DIM 256
#define NT    1024
#define NW    16              // waves per block
#define CPMAX 13              // waves 0-7 own 13 capsules, waves 8-15 own 12

__device__ __forceinline__ float bf_lo(unsigned u) { return __uint_as_float(u << 16); }
__device__ __forceinline__ float bf_hi(unsigned u) { return __uint_as_float(u & 0xffff0000u); }

__device__ __forceinline__ float wave_sum(float v) {
#pragma unroll
    for (int off = 32; off; off >>= 1) v += __shfl_xor(v, off);
    return v;
}

// Block sum WITHOUT leading barrier: caller must guarantee a __syncthreads()
// executed between the previous read of red[] and this call (WAR safety).
__device__ __forceinline__ float block_sum_nb(float v, float* red, int wave, int lane) {
    v = wave_sum(v);
    if (lane == 0) red[wave] = v;
    __syncthreads();
    float s = 0.f;
#pragma unroll
    for (int i = 0; i < NW; ++i) s += red[i];
    return s;
}

// Anchor = R10 (162us, best passing). R13 delta: NT 512->1024, capsules/wave
// 25 -> 13/12 split (wave<8 owns 13, mapping n = wave + 16*i; union covers
// 0..199 exactly once). Halves per-thread routing critical path AND drops
// persistent regs to u[13]=26 -> peak ~60 fits the allocator's 64-VGPR point
// honestly (no spill), allowing 2x16-wave blocks/CU. Phase structure, load
// depth (5-chunk), w_lds precompute, barrier layout: byte-identical to R10.
// DO NOT: fuse agreement+einsum accumulators (R3/R4 spill), LB(...,8)
// (R9: 32 VGPR), per-capsule sched_barrier (R6), LDS-split u (R7),
// lane-select gather of wave_sum results (R11: wrong c), inline e*inv in
// einsum / pre-staged exp phase-cuts (R12: +19us).
__global__ __launch_bounds__(NT, 2)
void dyr_kernel(const float* __restrict__ embeds,
                const float* __restrict__ weights,
                float* __restrict__ out_v,
                float* __restrict__ out_c)
{
    __shared__ float s_part[NW][D_DIM];   // 16 KB
    __shared__ float red[NW];
    __shared__ float b_lds[N_CAP];        // routing logits
    __shared__ float w_lds[N_CAP];        // einsum weights c_n * inv_n
    __shared__ float inv_lds[N_CAP];      // 1 / max(||x_n||, 1e-12)
    __shared__ float v_lds[D_DIM];

    const int b    = blockIdx.x;
    const int t    = threadIdx.x;
    const int wave = t >> 6;
    const int lane = t & 63;
    const int cpw  = (wave < 8) ? 13 : 12;   // wave-uniform

    // ---- init logits ----
    if (t < N_CAP) b_lds[t] = weights[(size_t)b * N_CAP + t];

    // ---- Load embeds ONCE; RAW x -> bf16 regs; 1/||x|| -> LDS.
    // wave w, lane l holds capsule n = w + 16*i, dims [4l, 4l+4).
    // Chunks of 5 in-flight float4 loads (R2/R10's proven depth). ----
    const float* eb = embeds + (size_t)b * (N_CAP * D_DIM) + lane * 4;

    uint2 u[CPMAX];   // 26 VGPRs, raw x packed bf16
#pragma unroll
    for (int cc = 0; cc < 3; ++cc) {            // chunks {5,5,3|2}
        const int base = cc * 5;
        const int cnt  = (cc == 2) ? (cpw - 10) : 5;   // wave-uniform
        float4 xs[5];
#pragma unroll
        for (int j = 0; j < 5; ++j) {
            if (j < cnt)
                xs[j] = *reinterpret_cast<const float4*>(eb + (wave + (base + j) * NW) * D_DIM);
        }
#pragma unroll
        for (int j = 0; j < 5; ++j) {
            if (j < cnt) {
                const float4 x = xs[j];
                float ss = fmaf(x.x, x.x, fmaf(x.y, x.y, fmaf(x.z, x.z, x.w * x.w)));
                ss = wave_sum(ss);
                if (lane == 0)
                    inv_lds[wave + (base + j) * NW] = 1.0f / fmaxf(sqrtf(ss), 1e-12f);
                union { __hip_bfloat16 h[4]; uint2 q; } pk;
                pk.h[0] = __float2bfloat16(x.x);
                pk.h[1] = __float2bfloat16(x.y);
                pk.h[2] = __float2bfloat16(x.z);
                pk.h[3] = __float2bfloat16(x.w);
                u[base + j] = pk.q;
            }
        }
    }
    __syncthreads();   // inv_lds/b_lds visible; WAR-guard for first block_sum_nb

    // ---- 3 routing iterations (R10's exact phase layout) ----
    for (int r = 0; r < 3; ++r) {
        // softmax denominator (no max-subtraction; |b| <= ~8, fp32 exp safe)
        const float e  = (t < N_CAP) ? __expf(b_lds[t]) : 0.0f;
        const float es = block_sum_nb(e, red, wave, lane);
        const float cs = (float)N_CAP / es;
        if (t < N_CAP) {
            const float cv = e * cs;             // c_n = softmax * N
            w_lds[t] = cv * inv_lds[t];          // einsum weight (norm folded)
            if (r == 2) out_c[(size_t)b * N_CAP + t] = cv;
        }
        __syncthreads();                          // w_lds visible

        // einsum partial: acc = sum_i w_i * x_i  (own capsules, w broadcast)
        float4 acc = make_float4(0.f, 0.f, 0.f, 0.f);
#pragma unroll
        for (int i = 0; i < CPMAX; ++i) {
            if (i < 12 || wave < 8) {
                const float wn = w_lds[wave + NW * i];   // wave-uniform broadcast
                acc.x = fmaf(wn, bf_lo(u[i].x), acc.x);
                acc.y = fmaf(wn, bf_hi(u[i].x), acc.y);
                acc.z = fmaf(wn, bf_lo(u[i].y), acc.z);
                acc.w = fmaf(wn, bf_hi(u[i].y), acc.w);
            }
        }
        *reinterpret_cast<float4*>(&s_part[wave][lane * 4]) = acc;
        __syncthreads();                          // s_part visible; red WAR-guard

        // cross-wave reduce + squash
        float sd = 0.f;
        if (t < D_DIM) {
#pragma unroll
            for (int w = 0; w < NW; ++w) sd += s_part[w][t];
        }
        const float ssn = block_sum_nb(sd * sd, red, wave, lane);
        if (t < D_DIM) {
            const float scale = ssn / (1.0f + ssn) * rsqrtf(ssn + 1e-9f);
            const float vd = scale * sd;
            v_lds[t] = vd;
            if (r == 2) out_v[(size_t)b * D_DIM + t] = vd;
        }

        if (r < 2) {
            __syncthreads();                      // v_lds visible; red WAR-guard
            const float4 vv = *reinterpret_cast<const float4*>(&v_lds[lane * 4]);
            // agreement: b_n += (x_n . v) * inv_n  (lane-0 owner-slot update)
#pragma unroll
            for (int i = 0; i < CPMAX; ++i) {
                if (i < 12 || wave < 8) {
                    float p = fmaf(bf_lo(u[i].x), vv.x,
                              fmaf(bf_hi(u[i].x), vv.y,
                              fmaf(bf_lo(u[i].y), vv.z,
                                   bf_hi(u[i].y) * vv.w)));
                    p = wave_sum(p);
                    if (lane == 0) {
                        const int n = wave + NW * i;
                        b_lds[n] = fmaf(p, inv_lds[n], b_lds[n]);
                    }
                }
            }
            __syncthreads();                      // b_lds visible for next iter
        }
    }
}

extern "C" void kernel_launch(void* const* d_in, const int* in_sizes, int n_in,
                              void* d_out, int out_size, void* d_ws, size_t ws_size,
                              hipStream_t stream) {
    const float* embeds  = (const float*)d_in[0];
    const float* weights = (const float*)d_in[1];
    float* out   = (float*)d_out;
    float* out_v = out;                                  // [2048, 256]
    float* out_c = out + (size_t)B_TOT * D_DIM;          // [2048, 200]

    dyr_kernel<<<B_TOT, NT, 0, stream>>>(embeds, weights, out_v, out_c);
}